// Round 18
// baseline (24069.922 us; speedup 1.0000x reference)
//
#include <hip/hip_runtime.h>
#include <math.h>

// VanillaRNN B=256,T=512,H=1024,O=10 — bit-exact replication of reference CPU
// fp32 trajectory. Decoded arithmetic (R5-R7 oracle): kc=512 panels, no-FMA
// chains (__fmul_rn/__fadd_rn, k ascending, panels joined in order), tanh =
// clamp ±7.99881172180175781 + fmaf Horner + IEEE div, no-FMA xp.
//
// R18 = R17 (PASSING, 18.6 ms; de-poisoned sync) + depth-2 software pipeline
// at FULL per-thread intensity (the single new variable). R15's pipeline
// regressed but was confounded (halved rows + L2-poisoning sync). Here:
// thread keeps 4 rows x 1 col (32 MACC / 12 loads per 4-k iter); two named
// prefetch buffer sets (8 float4 h + 4 W scalars), each sub-iter prefetches
// 2 iters ahead => ~24 loads in flight/wave, hiding the ~200cyc L2 latency
// of panel1-W. MACC chain order verbatim (loads reordered, math untouched).
// Sync (relaxed atomics + vL1 buffer_inv), XCD-local mapping, LDS-W panel0,
// epilogue: R17 verbatim.

#define HH 1024
#define TT 512
#define BB 256
#define OO 10
#define NG 16      // row groups (16 rows)
#define NCT 16     // col tiles (64 cols)
#define NTH 256
#define KH 512     // panel size

__device__ __forceinline__ float tanh_ref(float x) {
    const float kClamp = 7.99881172180175781f;
    float xc = fminf(fmaxf(x, -kClamp), kClamp);
    float x2 = __fmul_rn(xc, xc);
    float p = -2.76076847742355e-16f;
    p = fmaf(x2, p,  2.00018790482477e-13f);
    p = fmaf(x2, p, -8.60467152213735e-11f);
    p = fmaf(x2, p,  5.12229709037114e-08f);
    p = fmaf(x2, p,  1.48572235717979e-05f);
    p = fmaf(x2, p,  6.37261928875436e-04f);
    p = fmaf(x2, p,  4.89352455891786e-03f);
    p = __fmul_rn(xc, p);
    float q = 1.19825839466702e-06f;
    q = fmaf(x2, q, 1.18534705686654e-04f);
    q = fmaf(x2, q, 2.26843463243900e-03f);
    q = fmaf(x2, q, 4.89352518554385e-03f);
    float r = __fdiv_rn(p, q);
    return (fabsf(x) < 0.0004f) ? x : r;
}

#define MACC(acc, hv, wv) acc = __fadd_rn(acc, __fmul_rn(hv, wv))

// De-poisoned row-group sync (R17-proven): relaxed agent atomics (no per-poll
// cache ops), producer drain via __syncthreads (vmcnt 0), consumer vL1-only
// buffer_inv. Group is XCD-local (bid%8 invariant) => L2 is the common point.
#define GROUPSYNC_FAST(target_) {                                                   \
    __syncthreads();                                                                 \
    if (tid == 0) {                                                                  \
        __hip_atomic_fetch_add(&ctr[g], 1, __ATOMIC_RELAXED, __HIP_MEMORY_SCOPE_AGENT); \
        while (__hip_atomic_load(&ctr[g], __ATOMIC_RELAXED, __HIP_MEMORY_SCOPE_AGENT)   \
               < (target_))                                                          \
            __builtin_amdgcn_s_sleep(2);                                             \
    }                                                                                \
    __syncthreads();                                                                 \
    asm volatile("buffer_inv" ::: "memory");                                         \
}

// one prefetch-buffer load set: 8 float4 h (4 rows x 2 panels) + 4 W scalars
#define PF_LOAD(S, kn_) {                                                            \
    const int kn__ = (kn_);                                                          \
    pa0##S = *(const float4*)(h0p + kn__);                                           \
    pa1##S = *(const float4*)(h1p + kn__);                                           \
    pa2##S = *(const float4*)(h2p + kn__);                                           \
    pa3##S = *(const float4*)(h3p + kn__);                                           \
    pb0##S = *(const float4*)(h0p + KH + kn__);                                      \
    pb1##S = *(const float4*)(h1p + KH + kn__);                                      \
    pb2##S = *(const float4*)(h2p + KH + kn__);                                      \
    pb3##S = *(const float4*)(h3p + KH + kn__);                                      \
    v0##S = wp1[(size_t)(kn__ + 0) * HH];                                            \
    v1##S = wp1[(size_t)(kn__ + 1) * HH];                                            \
    v2##S = wp1[(size_t)(kn__ + 2) * HH];                                            \
    v3##S = wp1[(size_t)(kn__ + 3) * HH];                                            \
}

// consume one set at k-base kc_ (LDS W read here; MACC order = contract)
#define PF_USE(S, kc_) {                                                             \
    const float4 ha0 = pa0##S, ha1 = pa1##S, ha2 = pa2##S, ha3 = pa3##S;             \
    const float4 hb0 = pb0##S, hb1 = pb1##S, hb2 = pb2##S, hb3 = pb3##S;             \
    const float v0 = v0##S, v1 = v1##S, v2 = v2##S, v3 = v3##S;                      \
    const float w0 = wlds[(kc_) + 0][lane];                                          \
    const float w1 = wlds[(kc_) + 1][lane];                                          \
    const float w2 = wlds[(kc_) + 2][lane];                                          \
    const float w3 = wlds[(kc_) + 3][lane];                                          \
    MACC(a0, ha0.x, w0); MACC(a1, ha1.x, w0); MACC(a2, ha2.x, w0); MACC(a3, ha3.x, w0); \
    MACC(b0, hb0.x, v0); MACC(b1, hb1.x, v0); MACC(b2, hb2.x, v0); MACC(b3, hb3.x, v0); \
    MACC(a0, ha0.y, w1); MACC(a1, ha1.y, w1); MACC(a2, ha2.y, w1); MACC(a3, ha3.y, w1); \
    MACC(b0, hb0.y, v1); MACC(b1, hb1.y, v1); MACC(b2, hb2.y, v1); MACC(b3, hb3.y, v1); \
    MACC(a0, ha0.z, w2); MACC(a1, ha1.z, w2); MACC(a2, ha2.z, w2); MACC(a3, ha3.z, w2); \
    MACC(b0, hb0.z, v2); MACC(b1, hb1.z, v2); MACC(b2, hb2.z, v2); MACC(b3, hb3.z, v2); \
    MACC(a0, ha0.w, w3); MACC(a1, ha1.w, w3); MACC(a2, ha2.w, w3); MACC(a3, ha3.w, w3); \
    MACC(b0, hb0.w, v3); MACC(b1, hb1.w, v3); MACC(b2, hb2.w, v3); MACC(b3, hb3.w, v3); \
}

__global__ void __launch_bounds__(NTH, 1) rnn_persist(
    const float* __restrict__ x, const float* __restrict__ Whx,
    const float* __restrict__ Whh, const float* __restrict__ Wph,
    const float* __restrict__ bh, const float* __restrict__ bo,
    float* __restrict__ out, float* __restrict__ ws)
{
    __shared__ float wlds[KH][64];      // 128 KB: W[k<512][j0..j0+64)

    const int bid  = blockIdx.x;        // 0..255
    const int ct   = (bid >> 3) & 15;                 // col tile
    const int g    = ((bid & 7) << 1) | (bid >> 7);   // row group; bid%8 == g>>1
    const int tid  = threadIdx.x;
    const int w    = tid >> 6;          // wave 0..3
    const int lane = tid & 63;
    const int j0   = ct * 64;
    const int j    = j0 + lane;         // this thread's column
    const int r0w  = g * 16 + w * 4;    // this wave's first row

    float* hAbuf = ws;                  // [256][1024]
    float* hBbuf = ws + (BB * HH);
    int*   ctr   = (int*)(ws + 2 * BB * HH);  // [16], memset 0 pre-launch

    const float whx_j = Whx[j];
    const float bh_j  = bh[j];

    // ---- one-time W panel0 preload: 8192 float4 slots, coalesced ----
    #pragma unroll
    for (int i = 0; i < 32; ++i) {
        const int s = tid + i * NTH;     // 0..8191
        const int k = s >> 4;            // 0..511
        const int c = s & 15;            // float4 within 64-col row
        ((float4*)wlds)[s] = ((const float4*)(Whh + (size_t)k * HH + j0))[c];
    }

    // ---- zero-init hA rows, then group sync ----
    #pragma unroll
    for (int r = 0; r < 4; ++r)
        hAbuf[(size_t)(r0w + r) * HH + j] = 0.0f;
    GROUPSYNC_FAST(NCT)

    for (int t = 0; t < TT; ++t) {
        const float* hsrc = (t & 1) ? hBbuf : hAbuf;
        float*       hdst = (t & 1) ? hAbuf : hBbuf;

        const float* h0p = hsrc + (size_t)(r0w + 0) * HH;
        const float* h1p = hsrc + (size_t)(r0w + 1) * HH;
        const float* h2p = hsrc + (size_t)(r0w + 2) * HH;
        const float* h3p = hsrc + (size_t)(r0w + 3) * HH;
        const float* wp1 = Whh + (size_t)KH * HH + j;   // panel1 W[512+k][j]

        float a0 = 0.f, a1 = 0.f, a2 = 0.f, a3 = 0.f;   // panel0 chains
        float b0 = 0.f, b1 = 0.f, b2 = 0.f, b3 = 0.f;   // panel1 chains

        // ---- depth-2 pipeline: two named buffer sets (_0: even, _1: odd) ----
        float4 pa0_0, pa1_0, pa2_0, pa3_0, pb0_0, pb1_0, pb2_0, pb3_0;
        float  v0_0, v1_0, v2_0, v3_0;
        float4 pa0_1, pa1_1, pa2_1, pa3_1, pb0_1, pb1_1, pb2_1, pb3_1;
        float  v0_1, v1_1, v2_1, v3_1;
        PF_LOAD(_0, 0)
        PF_LOAD(_1, 4)

        #pragma unroll 1
        for (int k4 = 0; k4 < KH; k4 += 8) {
            // even sub-iter: consume _0 (k=k4..k4+3), prefetch _0 <- k4+8
            {
                const float4 ha0 = pa0_0, ha1 = pa1_0, ha2 = pa2_0, ha3 = pa3_0;
                const float4 hb0 = pb0_0, hb1 = pb1_0, hb2 = pb2_0, hb3 = pb3_0;
                const float v0 = v0_0, v1 = v1_0, v2 = v2_0, v3 = v3_0;
                PF_LOAD(_0, (k4 + 8) & (KH - 1))
                const float w0 = wlds[k4 + 0][lane];
                const float w1 = wlds[k4 + 1][lane];
                const float w2 = wlds[k4 + 2][lane];
                const float w3 = wlds[k4 + 3][lane];
                MACC(a0, ha0.x, w0); MACC(a1, ha1.x, w0); MACC(a2, ha2.x, w0); MACC(a3, ha3.x, w0);
                MACC(b0, hb0.x, v0); MACC(b1, hb1.x, v0); MACC(b2, hb2.x, v0); MACC(b3, hb3.x, v0);
                MACC(a0, ha0.y, w1); MACC(a1, ha1.y, w1); MACC(a2, ha2.y, w1); MACC(a3, ha3.y, w1);
                MACC(b0, hb0.y, v1); MACC(b1, hb1.y, v1); MACC(b2, hb2.y, v1); MACC(b3, hb3.y, v1);
                MACC(a0, ha0.z, w2); MACC(a1, ha1.z, w2); MACC(a2, ha2.z, w2); MACC(a3, ha3.z, w2);
                MACC(b0, hb0.z, v2); MACC(b1, hb1.z, v2); MACC(b2, hb2.z, v2); MACC(b3, hb3.z, v2);
                MACC(a0, ha0.w, w3); MACC(a1, ha1.w, w3); MACC(a2, ha2.w, w3); MACC(a3, ha3.w, w3);
                MACC(b0, hb0.w, v3); MACC(b1, hb1.w, v3); MACC(b2, hb2.w, v3); MACC(b3, hb3.w, v3);
            }
            // odd sub-iter: consume _1 (k=k4+4..k4+7), prefetch _1 <- k4+12
            {
                const float4 ha0 = pa0_1, ha1 = pa1_1, ha2 = pa2_1, ha3 = pa3_1;
                const float4 hb0 = pb0_1, hb1 = pb1_1, hb2 = pb2_1, hb3 = pb3_1;
                const float v0 = v0_1, v1 = v1_1, v2 = v2_1, v3 = v3_1;
                PF_LOAD(_1, (k4 + 12) & (KH - 1))
                const float w0 = wlds[k4 + 4][lane];
                const float w1 = wlds[k4 + 5][lane];
                const float w2 = wlds[k4 + 6][lane];
                const float w3 = wlds[k4 + 7][lane];
                MACC(a0, ha0.x, w0); MACC(a1, ha1.x, w0); MACC(a2, ha2.x, w0); MACC(a3, ha3.x, w0);
                MACC(b0, hb0.x, v0); MACC(b1, hb1.x, v0); MACC(b2, hb2.x, v0); MACC(b3, hb3.x, v0);
                MACC(a0, ha0.y, w1); MACC(a1, ha1.y, w1); MACC(a2, ha2.y, w1); MACC(a3, ha3.y, w1);
                MACC(b0, hb0.y, v1); MACC(b1, hb1.y, v1); MACC(b2, hb2.y, v1); MACC(b3, hb3.y, v1);
                MACC(a0, ha0.z, w2); MACC(a1, ha1.z, w2); MACC(a2, ha2.z, w2); MACC(a3, ha3.z, w2);
                MACC(b0, hb0.z, v2); MACC(b1, hb1.z, v2); MACC(b2, hb2.z, v2); MACC(b3, hb3.z, v2);
                MACC(a0, ha0.w, w3); MACC(a1, ha1.w, w3); MACC(a2, ha2.w, w3); MACC(a3, ha3.w, w3);
                MACC(b0, hb0.w, v3); MACC(b1, hb1.w, v3); MACC(b2, hb2.w, v3); MACC(b3, hb3.w, v3);
            }
        }

        // join panels (p0 then p1), xp, z, tanh, store (contract order)
        {
            const float m0 = __fadd_rn(a0, b0);
            const float m1 = __fadd_rn(a1, b1);
            const float m2 = __fadd_rn(a2, b2);
            const float m3 = __fadd_rn(a3, b3);
            const float xv0 = x[(r0w + 0) * TT + t];
            const float xv1 = x[(r0w + 1) * TT + t];
            const float xv2 = x[(r0w + 2) * TT + t];
            const float xv3 = x[(r0w + 3) * TT + t];
            hdst[(size_t)(r0w + 0) * HH + j] =
                tanh_ref(__fadd_rn(__fadd_rn(__fmul_rn(xv0, whx_j), bh_j), m0));
            hdst[(size_t)(r0w + 1) * HH + j] =
                tanh_ref(__fadd_rn(__fadd_rn(__fmul_rn(xv1, whx_j), bh_j), m1));
            hdst[(size_t)(r0w + 2) * HH + j] =
                tanh_ref(__fadd_rn(__fadd_rn(__fmul_rn(xv2, whx_j), bh_j), m2));
            hdst[(size_t)(r0w + 3) * HH + j] =
                tanh_ref(__fadd_rn(__fadd_rn(__fmul_rn(xv3, whx_j), bh_j), m3));
        }

        GROUPSYNC_FAST(NCT * (t + 2))
    }

    // ---- epilogue: out = h_final @ Wph + bo (h_final in hAbuf; TT even) ----
    if (ct == 0) {
        #pragma unroll 1
        for (int r = 0; r < 4; ++r) {
            const int row = r0w + r;
            #pragma unroll 1
            for (int o = 0; o < OO; ++o) {
                float v = 0.0f;
                #pragma unroll
                for (int m = 0; m < HH / 64; ++m) {
                    const int k = lane + (m << 6);
                    v = fmaf(hAbuf[(size_t)row * HH + k], Wph[k * OO + o], v);
                }
                #pragma unroll
                for (int s = 32; s > 0; s >>= 1) v += __shfl_down(v, s, 64);
                if (lane == 0) out[row * OO + o] = v + bo[o];
            }
        }
    }
}

extern "C" void kernel_launch(void* const* d_in, const int* in_sizes, int n_in,
                              void* d_out, int out_size, void* d_ws, size_t ws_size,
                              hipStream_t stream) {
    const float* x   = (const float*)d_in[0];
    const float* Whx = (const float*)d_in[1];
    const float* Whh = (const float*)d_in[2];
    const float* Wph = (const float*)d_in[3];
    const float* bh  = (const float*)d_in[4];
    const float* bo  = (const float*)d_in[5];
    float* out = (float*)d_out;
    float* ws  = (float*)d_ws;

    // reset row-group counters (R17 verbatim region, 64 B at 2 MB offset)
    hipMemsetAsync((char*)d_ws + (size_t)2 * BB * HH * 4, 0, NG * sizeof(int), stream);

    void* args[] = {(void*)&x, (void*)&Whx, (void*)&Whh, (void*)&Wph,
                    (void*)&bh, (void*)&bo, (void*)&out, (void*)&ws};
    hipLaunchCooperativeKernel((void*)rnn_persist, dim3(NG * NCT), dim3(NTH),
                               args, 0, stream);
}

// Round 19
// 20947.469 us; speedup vs baseline: 1.1491x; 1.1491x over previous
//
#include <hip/hip_runtime.h>
#include <math.h>

// VanillaRNN B=256,T=512,H=1024,O=10 — bit-exact replication of reference CPU
// fp32 trajectory. Decoded arithmetic (R5-R7 oracle): kc=512 panels, no-FMA
// chains (__fmul_rn/__fadd_rn, k ascending, panels joined in order), tanh =
// clamp ±7.99881172180175781 + fmaf Horner + IEEE div, no-FMA xp.
//
// R19: ALL of W in LDS (kills the panel1-W global stream — the source of the
// 20<->93 MB FETCH variance and the L2-luck bimodal replays; R18's explicit
// prefetch reverted, it regressed). Re-tile: WG = 32 rows x 32 cols, W slice
// [1024][32] = exactly 128 KB LDS, loaded once. Grid 256 = 8 groups x 32 cts;
// g = bid&7 => one row-group per XCD (32 WGs on its 32 CUs). Thread = 4 rows
// x 1 col; lane = col + 32*slot; wlds[k][col] is bank-exact (bank=col, upper
// half broadcast). h via 2-address float4 broadcasts. Sync = R17 de-poisoned
// macro (relaxed atomics + vL1 buffer_inv), fan-in 32. Chain order verbatim.

#define HH 1024
#define TT 512
#define BB 256
#define OO 10
#define NGRP 8     // row groups (32 rows) = XCDs
#define NCT 32     // col tiles (32 cols)
#define NTH 256
#define KH 512     // panel size

__device__ __forceinline__ float tanh_ref(float x) {
    const float kClamp = 7.99881172180175781f;
    float xc = fminf(fmaxf(x, -kClamp), kClamp);
    float x2 = __fmul_rn(xc, xc);
    float p = -2.76076847742355e-16f;
    p = fmaf(x2, p,  2.00018790482477e-13f);
    p = fmaf(x2, p, -8.60467152213735e-11f);
    p = fmaf(x2, p,  5.12229709037114e-08f);
    p = fmaf(x2, p,  1.48572235717979e-05f);
    p = fmaf(x2, p,  6.37261928875436e-04f);
    p = fmaf(x2, p,  4.89352455891786e-03f);
    p = __fmul_rn(xc, p);
    float q = 1.19825839466702e-06f;
    q = fmaf(x2, q, 1.18534705686654e-04f);
    q = fmaf(x2, q, 2.26843463243900e-03f);
    q = fmaf(x2, q, 4.89352518554385e-03f);
    float r = __fdiv_rn(p, q);
    return (fabsf(x) < 0.0004f) ? x : r;
}

#define MACC(acc, hv, wv) acc = __fadd_rn(acc, __fmul_rn(hv, wv))

// De-poisoned row-group sync (R17-proven): relaxed agent atomics, producer
// drain via __syncthreads (vmcnt 0), consumer vL1-only buffer_inv. Group is
// XCD-local (bid&7) => its L2 is the common coherence point.
#define GROUPSYNC_FAST(target_) {                                                   \
    __syncthreads();                                                                 \
    if (tid == 0) {                                                                  \
        __hip_atomic_fetch_add(&ctr[g], 1, __ATOMIC_RELAXED, __HIP_MEMORY_SCOPE_AGENT); \
        while (__hip_atomic_load(&ctr[g], __ATOMIC_RELAXED, __HIP_MEMORY_SCOPE_AGENT)   \
               < (target_))                                                          \
            __builtin_amdgcn_s_sleep(2);                                             \
    }                                                                                \
    __syncthreads();                                                                 \
    asm volatile("buffer_inv" ::: "memory");                                         \
}

__global__ void __launch_bounds__(NTH, 1) rnn_persist(
    const float* __restrict__ x, const float* __restrict__ Whx,
    const float* __restrict__ Whh, const float* __restrict__ Wph,
    const float* __restrict__ bh, const float* __restrict__ bo,
    float* __restrict__ out, float* __restrict__ ws)
{
    __shared__ float wlds[HH][32];      // 128 KB: W[all k][32-col slice]

    const int bid  = blockIdx.x;        // 0..255
    const int g    = bid & 7;           // row group == XCD
    const int ct   = bid >> 3;          // col tile 0..31
    const int tid  = threadIdx.x;
    const int w    = tid >> 6;          // wave 0..3
    const int lane = tid & 63;
    const int c32  = lane & 31;         // col within tile
    const int slot = lane >> 5;         // 0/1
    const int j0   = ct * 32;
    const int j    = j0 + c32;          // this thread's column
    const int r0w  = g * 32 + w * 8 + slot * 4;  // this thread's 4 rows

    float* hAbuf = ws;                  // [256][1024]
    float* hBbuf = ws + (BB * HH);
    int*   ctr   = (int*)(ws + 2 * BB * HH);  // [8], memset 0 pre-launch

    const float whx_j = Whx[j];
    const float bh_j  = bh[j];

    // ---- one-time W preload (ALL k): 8192 float4 slots, coalesced ----
    #pragma unroll
    for (int i = 0; i < 32; ++i) {
        const int s = tid + i * NTH;     // 0..8191
        const int k = s >> 3;            // 0..1023
        const int c4 = s & 7;            // float4 within 32-col row
        ((float4*)wlds)[s] = ((const float4*)(Whh + (size_t)k * HH + j0))[c4];
    }

    // ---- zero-init hA rows, then group sync ----
    #pragma unroll
    for (int r = 0; r < 4; ++r)
        hAbuf[(size_t)(r0w + r) * HH + j] = 0.0f;
    GROUPSYNC_FAST(NCT)

    for (int t = 0; t < TT; ++t) {
        const float* hsrc = (t & 1) ? hBbuf : hAbuf;
        float*       hdst = (t & 1) ? hAbuf : hBbuf;

        const float* h0p = hsrc + (size_t)(r0w + 0) * HH;
        const float* h1p = hsrc + (size_t)(r0w + 1) * HH;
        const float* h2p = hsrc + (size_t)(r0w + 2) * HH;
        const float* h3p = hsrc + (size_t)(r0w + 3) * HH;

        float a0 = 0.f, a1 = 0.f, a2 = 0.f, a3 = 0.f;   // panel0 chains
        float b0 = 0.f, b1 = 0.f, b2 = 0.f, b3 = 0.f;   // panel1 chains

        #pragma unroll 2
        for (int k4 = 0; k4 < KH; k4 += 4) {
            // h, both panels: float4 broadcasts (2 addrs per instr)
            const float4 ha0 = *(const float4*)(h0p + k4);
            const float4 ha1 = *(const float4*)(h1p + k4);
            const float4 ha2 = *(const float4*)(h2p + k4);
            const float4 ha3 = *(const float4*)(h3p + k4);
            const float4 hb0 = *(const float4*)(h0p + KH + k4);
            const float4 hb1 = *(const float4*)(h1p + KH + k4);
            const float4 hb2 = *(const float4*)(h2p + KH + k4);
            const float4 hb3 = *(const float4*)(h3p + KH + k4);
            // W, both panels, from LDS (bank = col: conflict-free + broadcast)
            const float w0 = wlds[k4 + 0][c32];
            const float w1 = wlds[k4 + 1][c32];
            const float w2 = wlds[k4 + 2][c32];
            const float w3 = wlds[k4 + 3][c32];
            const float v0 = wlds[KH + k4 + 0][c32];
            const float v1 = wlds[KH + k4 + 1][c32];
            const float v2 = wlds[KH + k4 + 2][c32];
            const float v3 = wlds[KH + k4 + 3][c32];
            // k ascending per panel — chain order is the correctness contract
            MACC(a0, ha0.x, w0); MACC(a1, ha1.x, w0); MACC(a2, ha2.x, w0); MACC(a3, ha3.x, w0);
            MACC(b0, hb0.x, v0); MACC(b1, hb1.x, v0); MACC(b2, hb2.x, v0); MACC(b3, hb3.x, v0);
            MACC(a0, ha0.y, w1); MACC(a1, ha1.y, w1); MACC(a2, ha2.y, w1); MACC(a3, ha3.y, w1);
            MACC(b0, hb0.y, v1); MACC(b1, hb1.y, v1); MACC(b2, hb2.y, v1); MACC(b3, hb3.y, v1);
            MACC(a0, ha0.z, w2); MACC(a1, ha1.z, w2); MACC(a2, ha2.z, w2); MACC(a3, ha3.z, w2);
            MACC(b0, hb0.z, v2); MACC(b1, hb1.z, v2); MACC(b2, hb2.z, v2); MACC(b3, hb3.z, v2);
            MACC(a0, ha0.w, w3); MACC(a1, ha1.w, w3); MACC(a2, ha2.w, w3); MACC(a3, ha3.w, w3);
            MACC(b0, hb0.w, v3); MACC(b1, hb1.w, v3); MACC(b2, hb2.w, v3); MACC(b3, hb3.w, v3);
        }

        // join panels (p0 then p1), xp, z, tanh, store (contract order)
        {
            const float m0 = __fadd_rn(a0, b0);
            const float m1 = __fadd_rn(a1, b1);
            const float m2 = __fadd_rn(a2, b2);
            const float m3 = __fadd_rn(a3, b3);
            const float xv0 = x[(r0w + 0) * TT + t];
            const float xv1 = x[(r0w + 1) * TT + t];
            const float xv2 = x[(r0w + 2) * TT + t];
            const float xv3 = x[(r0w + 3) * TT + t];
            hdst[(size_t)(r0w + 0) * HH + j] =
                tanh_ref(__fadd_rn(__fadd_rn(__fmul_rn(xv0, whx_j), bh_j), m0));
            hdst[(size_t)(r0w + 1) * HH + j] =
                tanh_ref(__fadd_rn(__fadd_rn(__fmul_rn(xv1, whx_j), bh_j), m1));
            hdst[(size_t)(r0w + 2) * HH + j] =
                tanh_ref(__fadd_rn(__fadd_rn(__fmul_rn(xv2, whx_j), bh_j), m2));
            hdst[(size_t)(r0w + 3) * HH + j] =
                tanh_ref(__fadd_rn(__fadd_rn(__fmul_rn(xv3, whx_j), bh_j), m3));
        }

        GROUPSYNC_FAST(NCT * (t + 2))
    }

    // ---- epilogue: out = h_final @ Wph + bo (h_final in hAbuf; TT even) ----
    if (ct == 0) {
        #pragma unroll 1
        for (int p = w; p < 32 * OO; p += 4) {
            const int rr = p / OO, o = p % OO;
            const int row = g * 32 + rr;
            float v = 0.0f;
            #pragma unroll
            for (int m = 0; m < HH / 64; ++m) {
                const int k = lane + (m << 6);
                v = fmaf(hAbuf[(size_t)row * HH + k], Wph[k * OO + o], v);
            }
            #pragma unroll
            for (int s = 32; s > 0; s >>= 1) v += __shfl_down(v, s, 64);
            if (lane == 0) out[row * OO + o] = v + bo[o];
        }
    }
}

extern "C" void kernel_launch(void* const* d_in, const int* in_sizes, int n_in,
                              void* d_out, int out_size, void* d_ws, size_t ws_size,
                              hipStream_t stream) {
    const float* x   = (const float*)d_in[0];
    const float* Whx = (const float*)d_in[1];
    const float* Whh = (const float*)d_in[2];
    const float* Wph = (const float*)d_in[3];
    const float* bh  = (const float*)d_in[4];
    const float* bo  = (const float*)d_in[5];
    float* out = (float*)d_out;
    float* ws  = (float*)d_ws;

    // reset row-group counters (8 ints at the 2 MB mark — proven region)
    hipMemsetAsync((char*)d_ws + (size_t)2 * BB * HH * 4, 0, 64, stream);

    void* args[] = {(void*)&x, (void*)&Whx, (void*)&Whh, (void*)&Wph,
                    (void*)&bh, (void*)&bo, (void*)&out, (void*)&ws};
    hipLaunchCooperativeKernel((void*)rnn_persist, dim3(NGRP * NCT), dim3(NTH),
                               args, 0, stream);
}

// Round 20
// 15779.266 us; speedup vs baseline: 1.5254x; 1.3275x over previous
//
#include <hip/hip_runtime.h>
#include <math.h>

// VanillaRNN B=256,T=512,H=1024,O=10 — bit-exact replication of reference CPU
// fp32 trajectory. Decoded arithmetic (R5-R7 oracle): kc=512 panels, no-FMA
// chains (__fmul_rn/__fadd_rn, k ascending, panels joined in order), tanh =
// clamp ±7.99881172180175781 + fmaf Horner + IEEE div, no-FMA xp.
//
// R20 = R19 (PASSING, deterministic 20.9 ms, all-W-in-LDS, FETCH 23 MB) with
// ONE variable: 512 threads (2 waves/SIMD, was 1) — thread = 2 rows x 1 col.
// R15/R16's "TLP doesn't help" verdicts predate the R17 sync de-poisoning and
// are void; this is TLP's first clean-cache test. Per-SIMD VALU unchanged;
// wave 2 fills wave 1's ~200cyc L2-hit h-load stalls. Everything else R19
// verbatim: W slice [1024][32] = 128 KB LDS loaded once, grid 256 = 8
// XCD-local groups x 32 cts, de-poisoned sync, chain order contract.

#define HH 1024
#define TT 512
#define BB 256
#define OO 10
#define NGRP 8     // row groups (32 rows) = XCDs
#define NCT 32     // col tiles (32 cols)
#define NTH 512
#define KH 512     // panel size

__device__ __forceinline__ float tanh_ref(float x) {
    const float kClamp = 7.99881172180175781f;
    float xc = fminf(fmaxf(x, -kClamp), kClamp);
    float x2 = __fmul_rn(xc, xc);
    float p = -2.76076847742355e-16f;
    p = fmaf(x2, p,  2.00018790482477e-13f);
    p = fmaf(x2, p, -8.60467152213735e-11f);
    p = fmaf(x2, p,  5.12229709037114e-08f);
    p = fmaf(x2, p,  1.48572235717979e-05f);
    p = fmaf(x2, p,  6.37261928875436e-04f);
    p = fmaf(x2, p,  4.89352455891786e-03f);
    p = __fmul_rn(xc, p);
    float q = 1.19825839466702e-06f;
    q = fmaf(x2, q, 1.18534705686654e-04f);
    q = fmaf(x2, q, 2.26843463243900e-03f);
    q = fmaf(x2, q, 4.89352518554385e-03f);
    float r = __fdiv_rn(p, q);
    return (fabsf(x) < 0.0004f) ? x : r;
}

#define MACC(acc, hv, wv) acc = __fadd_rn(acc, __fmul_rn(hv, wv))

// De-poisoned row-group sync (R17-proven): relaxed agent atomics, producer
// drain via __syncthreads (vmcnt 0), consumer vL1-only buffer_inv. Group is
// XCD-local (bid&7) => its L2 is the common coherence point.
#define GROUPSYNC_FAST(target_) {                                                   \
    __syncthreads();                                                                 \
    if (tid == 0) {                                                                  \
        __hip_atomic_fetch_add(&ctr[g], 1, __ATOMIC_RELAXED, __HIP_MEMORY_SCOPE_AGENT); \
        while (__hip_atomic_load(&ctr[g], __ATOMIC_RELAXED, __HIP_MEMORY_SCOPE_AGENT)   \
               < (target_))                                                          \
            __builtin_amdgcn_s_sleep(2);                                             \
    }                                                                                \
    __syncthreads();                                                                 \
    asm volatile("buffer_inv" ::: "memory");                                         \
}

__global__ void __launch_bounds__(NTH, 1) rnn_persist(
    const float* __restrict__ x, const float* __restrict__ Whx,
    const float* __restrict__ Whh, const float* __restrict__ Wph,
    const float* __restrict__ bh, const float* __restrict__ bo,
    float* __restrict__ out, float* __restrict__ ws)
{
    __shared__ float wlds[HH][32];      // 128 KB: W[all k][32-col slice]

    const int bid  = blockIdx.x;        // 0..255
    const int g    = bid & 7;           // row group == XCD
    const int ct   = bid >> 3;          // col tile 0..31
    const int tid  = threadIdx.x;
    const int w    = tid >> 6;          // wave 0..7
    const int lane = tid & 63;
    const int c32  = lane & 31;         // col within tile
    const int slot = lane >> 5;         // 0/1
    const int j0   = ct * 32;
    const int j    = j0 + c32;          // this thread's column
    const int r0w  = g * 32 + w * 4 + slot * 2;  // this thread's 2 rows

    float* hAbuf = ws;                  // [256][1024]
    float* hBbuf = ws + (BB * HH);
    int*   ctr   = (int*)(ws + 2 * BB * HH);  // [8], memset 0 pre-launch

    const float whx_j = Whx[j];
    const float bh_j  = bh[j];

    // ---- one-time W preload (ALL k): 8192 float4 slots, coalesced ----
    #pragma unroll
    for (int i = 0; i < 16; ++i) {
        const int s = tid + i * NTH;     // 0..8191
        const int k = s >> 3;            // 0..1023
        const int c4 = s & 7;            // float4 within 32-col row
        ((float4*)wlds)[s] = ((const float4*)(Whh + (size_t)k * HH + j0))[c4];
    }

    // ---- zero-init hA rows, then group sync ----
    hAbuf[(size_t)(r0w + 0) * HH + j] = 0.0f;
    hAbuf[(size_t)(r0w + 1) * HH + j] = 0.0f;
    GROUPSYNC_FAST(NCT)

    for (int t = 0; t < TT; ++t) {
        const float* hsrc = (t & 1) ? hBbuf : hAbuf;
        float*       hdst = (t & 1) ? hAbuf : hBbuf;

        const float* h0p = hsrc + (size_t)(r0w + 0) * HH;
        const float* h1p = hsrc + (size_t)(r0w + 1) * HH;

        float a0 = 0.f, a1 = 0.f;   // panel0 chains (2 rows)
        float b0 = 0.f, b1 = 0.f;   // panel1 chains

        #pragma unroll 2
        for (int k4 = 0; k4 < KH; k4 += 4) {
            const float4 ha0 = *(const float4*)(h0p + k4);
            const float4 ha1 = *(const float4*)(h1p + k4);
            const float4 hb0 = *(const float4*)(h0p + KH + k4);
            const float4 hb1 = *(const float4*)(h1p + KH + k4);
            // W, both panels, from LDS (bank = col: conflict-free + broadcast)
            const float w0 = wlds[k4 + 0][c32];
            const float w1 = wlds[k4 + 1][c32];
            const float w2 = wlds[k4 + 2][c32];
            const float w3 = wlds[k4 + 3][c32];
            const float v0 = wlds[KH + k4 + 0][c32];
            const float v1 = wlds[KH + k4 + 1][c32];
            const float v2 = wlds[KH + k4 + 2][c32];
            const float v3 = wlds[KH + k4 + 3][c32];
            // k ascending per panel — chain order is the correctness contract
            MACC(a0, ha0.x, w0); MACC(a1, ha1.x, w0);
            MACC(b0, hb0.x, v0); MACC(b1, hb1.x, v0);
            MACC(a0, ha0.y, w1); MACC(a1, ha1.y, w1);
            MACC(b0, hb0.y, v1); MACC(b1, hb1.y, v1);
            MACC(a0, ha0.z, w2); MACC(a1, ha1.z, w2);
            MACC(b0, hb0.z, v2); MACC(b1, hb1.z, v2);
            MACC(a0, ha0.w, w3); MACC(a1, ha1.w, w3);
            MACC(b0, hb0.w, v3); MACC(b1, hb1.w, v3);
        }

        // join panels (p0 then p1), xp, z, tanh, store (contract order)
        {
            const float m0 = __fadd_rn(a0, b0);
            const float m1 = __fadd_rn(a1, b1);
            const float xv0 = x[(r0w + 0) * TT + t];
            const float xv1 = x[(r0w + 1) * TT + t];
            hdst[(size_t)(r0w + 0) * HH + j] =
                tanh_ref(__fadd_rn(__fadd_rn(__fmul_rn(xv0, whx_j), bh_j), m0));
            hdst[(size_t)(r0w + 1) * HH + j] =
                tanh_ref(__fadd_rn(__fadd_rn(__fmul_rn(xv1, whx_j), bh_j), m1));
        }

        GROUPSYNC_FAST(NCT * (t + 2))
    }

    // ---- epilogue: out = h_final @ Wph + bo (h_final in hAbuf; TT even) ----
    if (ct == 0) {
        #pragma unroll 1
        for (int p = w; p < 32 * OO; p += 8) {
            const int rr = p / OO, o = p % OO;
            const int row = g * 32 + rr;
            float v = 0.0f;
            #pragma unroll
            for (int m = 0; m < HH / 64; ++m) {
                const int k = lane + (m << 6);
                v = fmaf(hAbuf[(size_t)row * HH + k], Wph[k * OO + o], v);
            }
            #pragma unroll
            for (int s = 32; s > 0; s >>= 1) v += __shfl_down(v, s, 64);
            if (lane == 0) out[row * OO + o] = v + bo[o];
        }
    }
}

extern "C" void kernel_launch(void* const* d_in, const int* in_sizes, int n_in,
                              void* d_out, int out_size, void* d_ws, size_t ws_size,
                              hipStream_t stream) {
    const float* x   = (const float*)d_in[0];
    const float* Whx = (const float*)d_in[1];
    const float* Whh = (const float*)d_in[2];
    const float* Wph = (const float*)d_in[3];
    const float* bh  = (const float*)d_in[4];
    const float* bo  = (const float*)d_in[5];
    float* out = (float*)d_out;
    float* ws  = (float*)d_ws;

    // reset row-group counters (8 ints at the 2 MB mark — proven region)
    hipMemsetAsync((char*)d_ws + (size_t)2 * BB * HH * 4, 0, 64, stream);

    void* args[] = {(void*)&x, (void*)&Whx, (void*)&Whh, (void*)&Wph,
                    (void*)&bh, (void*)&bo, (void*)&out, (void*)&ws};
    hipLaunchCooperativeKernel((void*)rnn_persist, dim3(NGRP * NCT), dim3(NTH),
                               args, 0, stream);
}

// Round 21
// 15022.629 us; speedup vs baseline: 1.6022x; 1.0504x over previous
//
#include <hip/hip_runtime.h>
#include <math.h>

// VanillaRNN B=256,T=512,H=1024,O=10 — bit-exact replication of reference CPU
// fp32 trajectory. Decoded arithmetic (R5-R7 oracle): kc=512 panels, no-FMA
// chains (__fmul_rn/__fadd_rn, k ascending, panels joined in order), tanh =
// clamp ±7.99881172180175781 + fmaf Horner + IEEE div, no-FMA xp.
//
// R21 = R20 (PASSING, 15.8 ms, 2 waves/SIMD, all-W-in-LDS) with ONE variable:
// W LDS layout transposed + XOR-swizzled -> b128 W reads.
//   store: wldsT[c][k ^ ((c&7)<<2)] = W[k][j0+c]
//   read:  float4 @ wldsT[c][k4 ^ swz] = {W[k4..k4+3][j]}  (swizzle self-inverts)
// Banks: lane c covers (k4^4(c&7))+{0..3}; each 8-lane group = all 32 banks
// once; upper half broadcasts => canonical conflict-free ds_read_b128.
// LDS instrs/wave/step: 1024 scalar b32 -> 256 b128 (the R20 wall: ~47K ->
// ~25K cyc/CU/step). Chain order, h-loads, de-poisoned sync, XCD-local
// mapping, epilogue: R20 verbatim.

#define HH 1024
#define TT 512
#define BB 256
#define OO 10
#define NGRP 8     // row groups (32 rows) = XCDs
#define NCT 32     // col tiles (32 cols)
#define NTH 512
#define KH 512     // panel size

__device__ __forceinline__ float tanh_ref(float x) {
    const float kClamp = 7.99881172180175781f;
    float xc = fminf(fmaxf(x, -kClamp), kClamp);
    float x2 = __fmul_rn(xc, xc);
    float p = -2.76076847742355e-16f;
    p = fmaf(x2, p,  2.00018790482477e-13f);
    p = fmaf(x2, p, -8.60467152213735e-11f);
    p = fmaf(x2, p,  5.12229709037114e-08f);
    p = fmaf(x2, p,  1.48572235717979e-05f);
    p = fmaf(x2, p,  6.37261928875436e-04f);
    p = fmaf(x2, p,  4.89352455891786e-03f);
    p = __fmul_rn(xc, p);
    float q = 1.19825839466702e-06f;
    q = fmaf(x2, q, 1.18534705686654e-04f);
    q = fmaf(x2, q, 2.26843463243900e-03f);
    q = fmaf(x2, q, 4.89352518554385e-03f);
    float r = __fdiv_rn(p, q);
    return (fabsf(x) < 0.0004f) ? x : r;
}

#define MACC(acc, hv, wv) acc = __fadd_rn(acc, __fmul_rn(hv, wv))

// De-poisoned row-group sync (R17-proven): relaxed agent atomics, producer
// drain via __syncthreads (vmcnt 0), consumer vL1-only buffer_inv. Group is
// XCD-local (bid&7) => its L2 is the common coherence point.
#define GROUPSYNC_FAST(target_) {                                                   \
    __syncthreads();                                                                 \
    if (tid == 0) {                                                                  \
        __hip_atomic_fetch_add(&ctr[g], 1, __ATOMIC_RELAXED, __HIP_MEMORY_SCOPE_AGENT); \
        while (__hip_atomic_load(&ctr[g], __ATOMIC_RELAXED, __HIP_MEMORY_SCOPE_AGENT)   \
               < (target_))                                                          \
            __builtin_amdgcn_s_sleep(2);                                             \
    }                                                                                \
    __syncthreads();                                                                 \
    asm volatile("buffer_inv" ::: "memory");                                         \
}

__global__ void __launch_bounds__(NTH, 1) rnn_persist(
    const float* __restrict__ x, const float* __restrict__ Whx,
    const float* __restrict__ Whh, const float* __restrict__ Wph,
    const float* __restrict__ bh, const float* __restrict__ bo,
    float* __restrict__ out, float* __restrict__ ws)
{
    __shared__ float wldsT[32][1024];   // 128 KB: col-major W slice, k XOR-swizzled

    const int bid  = blockIdx.x;        // 0..255
    const int g    = bid & 7;           // row group == XCD
    const int ct   = bid >> 3;          // col tile 0..31
    const int tid  = threadIdx.x;
    const int w    = tid >> 6;          // wave 0..7
    const int lane = tid & 63;
    const int c32  = lane & 31;         // col within tile
    const int slot = lane >> 5;         // 0/1
    const int j0   = ct * 32;
    const int j    = j0 + c32;          // this thread's column
    const int r0w  = g * 32 + w * 4 + slot * 2;  // this thread's 2 rows
    const int swz  = (c32 & 7) << 2;    // per-thread XOR swizzle (bits 2..4)

    float* hAbuf = ws;                  // [256][1024]
    float* hBbuf = ws + (BB * HH);
    int*   ctr   = (int*)(ws + 2 * BB * HH);  // [8], memset 0 pre-launch

    const float whx_j = Whx[j];
    const float bh_j  = bh[j];

    // ---- one-time W preload into transposed+swizzled layout ----
    // e = (k,c) pairs k-major: coalesced 32-lane scalar reads of W[k][j0..j0+31];
    // scatter b32 writes to wldsT[c][k ^ ((c&7)<<2)] (4-way alias, one-time).
    #pragma unroll
    for (int i = 0; i < 64; ++i) {
        const int e = tid + i * NTH;     // 0..32767
        const int k = e >> 5;            // 0..1023
        const int c = e & 31;
        wldsT[c][k ^ ((c & 7) << 2)] = Whh[(size_t)k * HH + j0 + c];
    }

    // ---- zero-init hA rows, then group sync ----
    hAbuf[(size_t)(r0w + 0) * HH + j] = 0.0f;
    hAbuf[(size_t)(r0w + 1) * HH + j] = 0.0f;
    GROUPSYNC_FAST(NCT)

    for (int t = 0; t < TT; ++t) {
        const float* hsrc = (t & 1) ? hBbuf : hAbuf;
        float*       hdst = (t & 1) ? hAbuf : hBbuf;

        const float* h0p = hsrc + (size_t)(r0w + 0) * HH;
        const float* h1p = hsrc + (size_t)(r0w + 1) * HH;
        const float* wrow = wldsT[c32];

        float a0 = 0.f, a1 = 0.f;   // panel0 chains (2 rows)
        float b0 = 0.f, b1 = 0.f;   // panel1 chains

        #pragma unroll 2
        for (int k4 = 0; k4 < KH; k4 += 4) {
            const float4 ha0 = *(const float4*)(h0p + k4);
            const float4 ha1 = *(const float4*)(h1p + k4);
            const float4 hb0 = *(const float4*)(h0p + KH + k4);
            const float4 hb1 = *(const float4*)(h1p + KH + k4);
            // W via swizzled b128: w4 = {W[k4..k4+3][j]}, v4 = {W[512+k4..][j]}
            const float4 w4 = *(const float4*)(wrow + (k4 ^ swz));
            const float4 v4 = *(const float4*)(wrow + ((KH + k4) ^ swz));
            // k ascending per panel — chain order is the correctness contract
            MACC(a0, ha0.x, w4.x); MACC(a1, ha1.x, w4.x);
            MACC(b0, hb0.x, v4.x); MACC(b1, hb1.x, v4.x);
            MACC(a0, ha0.y, w4.y); MACC(a1, ha1.y, w4.y);
            MACC(b0, hb0.y, v4.y); MACC(b1, hb1.y, v4.y);
            MACC(a0, ha0.z, w4.z); MACC(a1, ha1.z, w4.z);
            MACC(b0, hb0.z, v4.z); MACC(b1, hb1.z, v4.z);
            MACC(a0, ha0.w, w4.w); MACC(a1, ha1.w, w4.w);
            MACC(b0, hb0.w, v4.w); MACC(b1, hb1.w, v4.w);
        }

        // join panels (p0 then p1), xp, z, tanh, store (contract order)
        {
            const float m0 = __fadd_rn(a0, b0);
            const float m1 = __fadd_rn(a1, b1);
            const float xv0 = x[(r0w + 0) * TT + t];
            const float xv1 = x[(r0w + 1) * TT + t];
            hdst[(size_t)(r0w + 0) * HH + j] =
                tanh_ref(__fadd_rn(__fadd_rn(__fmul_rn(xv0, whx_j), bh_j), m0));
            hdst[(size_t)(r0w + 1) * HH + j] =
                tanh_ref(__fadd_rn(__fadd_rn(__fmul_rn(xv1, whx_j), bh_j), m1));
        }

        GROUPSYNC_FAST(NCT * (t + 2))
    }

    // ---- epilogue: out = h_final @ Wph + bo (h_final in hAbuf; TT even) ----
    if (ct == 0) {
        #pragma unroll 1
        for (int p = w; p < 32 * OO; p += 8) {
            const int rr = p / OO, o = p % OO;
            const int row = g * 32 + rr;
            float v = 0.0f;
            #pragma unroll
            for (int m = 0; m < HH / 64; ++m) {
                const int k = lane + (m << 6);
                v = fmaf(hAbuf[(size_t)row * HH + k], Wph[k * OO + o], v);
            }
            #pragma unroll
            for (int s = 32; s > 0; s >>= 1) v += __shfl_down(v, s, 64);
            if (lane == 0) out[row * OO + o] = v + bo[o];
        }
    }
}

extern "C" void kernel_launch(void* const* d_in, const int* in_sizes, int n_in,
                              void* d_out, int out_size, void* d_ws, size_t ws_size,
                              hipStream_t stream) {
    const float* x   = (const float*)d_in[0];
    const float* Whx = (const float*)d_in[1];
    const float* Whh = (const float*)d_in[2];
    const float* Wph = (const float*)d_in[3];
    const float* bh  = (const float*)d_in[4];
    const float* bo  = (const float*)d_in[5];
    float* out = (float*)d_out;
    float* ws  = (float*)d_ws;

    // reset row-group counters (8 ints at the 2 MB mark — proven region)
    hipMemsetAsync((char*)d_ws + (size_t)2 * BB * HH * 4, 0, 64, stream);

    void* args[] = {(void*)&x, (void*)&Whx, (void*)&Whh, (void*)&Wph,
                    (void*)&bh, (void*)&bo, (void*)&out, (void*)&ws};
    hipLaunchCooperativeKernel((void*)rnn_persist, dim3(NGRP * NCT), dim3(NTH),
                               args, 0, stream);
}

// Round 22
// 15020.331 us; speedup vs baseline: 1.6025x; 1.0002x over previous
//
#include <hip/hip_runtime.h>
#include <math.h>

// VanillaRNN B=256,T=512,H=1024,O=10 — bit-exact replication of reference CPU
// fp32 trajectory. Decoded arithmetic (R5-R7 oracle): kc=512 panels, no-FMA
// chains (__fmul_rn/__fadd_rn, k ascending, panels joined in order), tanh =
// clamp ±7.99881172180175781 + fmaf Horner + IEEE div, no-FMA xp.
//
// R22 = R21 with the bank-conflict actually fixed + 4 waves/SIMD:
//  - R21's [c][k] XOR layout had unavoidable 4-way conflicts with 32 unique
//    cols/wave (pigeonhole on 8 bank-starts; SQ_LDS_BANK_CONFLICT 1.075e9).
//  - New wave geometry: 8 cols x 8 rows per wave (lane = c8 + 8*r8). Only 8
//    unique W addresses per b128; bank-starts {k4^4m} cover all 32 banks
//    exactly once -> conflict-free, 8-way broadcast free.
//  - NTH 1024 (16 waves, 4/SIMD; thread = 1 row x 1 col): 2x latency hiding
//    vs R20/R21. 16 waves = 4x4 blocks of 8x8 over the 32x32 (row,col) tile.
//  - W slice [32 cols][1024 k] swizzled, 128 KB LDS, loaded once (R21 preload
//    verbatim). Grid 256 = 8 XCD-local groups x 32 cts. De-poisoned sync.
//  - Chain contract unchanged: a=panel0 k-ascending, b=panel1, m=fadd(a,b),
//    no-FMA xp, verbatim tanh, ordered join.

#define HH 1024
#define TT 512
#define BB 256
#define OO 10
#define NGRP 8     // row groups (32 rows) = XCDs
#define NCT 32     // col tiles (32 cols)
#define NTH 1024
#define KH 512     // panel size

__device__ __forceinline__ float tanh_ref(float x) {
    const float kClamp = 7.99881172180175781f;
    float xc = fminf(fmaxf(x, -kClamp), kClamp);
    float x2 = __fmul_rn(xc, xc);
    float p = -2.76076847742355e-16f;
    p = fmaf(x2, p,  2.00018790482477e-13f);
    p = fmaf(x2, p, -8.60467152213735e-11f);
    p = fmaf(x2, p,  5.12229709037114e-08f);
    p = fmaf(x2, p,  1.48572235717979e-05f);
    p = fmaf(x2, p,  6.37261928875436e-04f);
    p = fmaf(x2, p,  4.89352455891786e-03f);
    p = __fmul_rn(xc, p);
    float q = 1.19825839466702e-06f;
    q = fmaf(x2, q, 1.18534705686654e-04f);
    q = fmaf(x2, q, 2.26843463243900e-03f);
    q = fmaf(x2, q, 4.89352518554385e-03f);
    float r = __fdiv_rn(p, q);
    return (fabsf(x) < 0.0004f) ? x : r;
}

#define MACC(acc, hv, wv) acc = __fadd_rn(acc, __fmul_rn(hv, wv))

// De-poisoned row-group sync (R17-proven): relaxed agent atomics, producer
// drain via __syncthreads (vmcnt 0), consumer vL1-only buffer_inv. Group is
// XCD-local (bid&7) => its L2 is the common coherence point.
#define GROUPSYNC_FAST(target_) {                                                   \
    __syncthreads();                                                                 \
    if (tid == 0) {                                                                  \
        __hip_atomic_fetch_add(&ctr[g], 1, __ATOMIC_RELAXED, __HIP_MEMORY_SCOPE_AGENT); \
        while (__hip_atomic_load(&ctr[g], __ATOMIC_RELAXED, __HIP_MEMORY_SCOPE_AGENT)   \
               < (target_))                                                          \
            __builtin_amdgcn_s_sleep(2);                                             \
    }                                                                                \
    __syncthreads();                                                                 \
    asm volatile("buffer_inv" ::: "memory");                                         \
}

__global__ void __launch_bounds__(NTH, 1) rnn_persist(
    const float* __restrict__ x, const float* __restrict__ Whx,
    const float* __restrict__ Whh, const float* __restrict__ Wph,
    const float* __restrict__ bh, const float* __restrict__ bo,
    float* __restrict__ out, float* __restrict__ ws)
{
    __shared__ float wldsT[32][1024];   // 128 KB: col-major W slice, k XOR-swizzled

    const int bid  = blockIdx.x;        // 0..255
    const int g    = bid & 7;           // row group == XCD
    const int ct   = bid >> 3;          // col tile 0..31
    const int tid  = threadIdx.x;
    const int w    = tid >> 6;          // wave 0..15
    const int lane = tid & 63;
    const int c8   = lane & 7;          // col within wave's 8-col block
    const int r8   = lane >> 3;         // row within wave's 8-row block
    const int c32  = (w & 3) * 8 + c8;  // col within 32-col tile
    const int row_l= (w >> 2) * 8 + r8; // row within 32-row group
    const int j0   = ct * 32;
    const int j    = j0 + c32;          // this thread's column
    const int row  = g * 32 + row_l;    // this thread's (single) row
    const int swz  = (c32 & 7) << 2;    // XOR swizzle (bits 2..4)

    float* hAbuf = ws;                  // [256][1024]
    float* hBbuf = ws + (BB * HH);
    int*   ctr   = (int*)(ws + 2 * BB * HH);  // [8], memset 0 pre-launch

    const float whx_j = Whx[j];
    const float bh_j  = bh[j];

    // ---- one-time W preload into transposed+swizzled layout (R21 verbatim) ----
    #pragma unroll
    for (int i = 0; i < 32; ++i) {
        const int e = tid + i * NTH;     // 0..32767
        const int k = e >> 5;            // 0..1023
        const int c = e & 31;
        wldsT[c][k ^ ((c & 7) << 2)] = Whh[(size_t)k * HH + j0 + c];
    }

    // ---- zero-init hA row, then group sync ----
    hAbuf[(size_t)row * HH + j] = 0.0f;
    GROUPSYNC_FAST(NCT)

    for (int t = 0; t < TT; ++t) {
        const float* hsrc = (t & 1) ? hBbuf : hAbuf;
        float*       hdst = (t & 1) ? hAbuf : hBbuf;

        const float* hp = hsrc + (size_t)row * HH;
        const float* wrow = wldsT[c32];

        float a = 0.f;   // panel0 chain
        float b = 0.f;   // panel1 chain

        #pragma unroll 4
        for (int k4 = 0; k4 < KH; k4 += 4) {
            const float4 ha = *(const float4*)(hp + k4);
            const float4 hb = *(const float4*)(hp + KH + k4);
            // W via swizzled b128: 8 unique addrs/wave -> all 32 banks once
            const float4 w4 = *(const float4*)(wrow + (k4 ^ swz));
            const float4 v4 = *(const float4*)(wrow + ((KH + k4) ^ swz));
            // k ascending per panel — chain order is the correctness contract
            MACC(a, ha.x, w4.x); MACC(b, hb.x, v4.x);
            MACC(a, ha.y, w4.y); MACC(b, hb.y, v4.y);
            MACC(a, ha.z, w4.z); MACC(b, hb.z, v4.z);
            MACC(a, ha.w, w4.w); MACC(b, hb.w, v4.w);
        }

        // join panels (p0 then p1), xp, z, tanh, store (contract order)
        {
            const float m = __fadd_rn(a, b);
            const float xv = x[(size_t)row * TT + t];
            hdst[(size_t)row * HH + j] =
                tanh_ref(__fadd_rn(__fadd_rn(__fmul_rn(xv, whx_j), bh_j), m));
        }

        GROUPSYNC_FAST(NCT * (t + 2))
    }

    // ---- epilogue: out = h_final @ Wph + bo (h_final in hAbuf; TT even) ----
    if (ct == 0) {
        #pragma unroll 1
        for (int p = w; p < 32 * OO; p += 16) {
            const int rr = p / OO, o = p % OO;
            const int orow = g * 32 + rr;
            float v = 0.0f;
            #pragma unroll
            for (int m = 0; m < HH / 64; ++m) {
                const int k = lane + (m << 6);
                v = fmaf(hAbuf[(size_t)orow * HH + k], Wph[k * OO + o], v);
            }
            #pragma unroll
            for (int s = 32; s > 0; s >>= 1) v += __shfl_down(v, s, 64);
            if (lane == 0) out[orow * OO + o] = v + bo[o];
        }
    }
}

extern "C" void kernel_launch(void* const* d_in, const int* in_sizes, int n_in,
                              void* d_out, int out_size, void* d_ws, size_t ws_size,
                              hipStream_t stream) {
    const float* x   = (const float*)d_in[0];
    const float* Whx = (const float*)d_in[1];
    const float* Whh = (const float*)d_in[2];
    const float* Wph = (const float*)d_in[3];
    const float* bh  = (const float*)d_in[4];
    const float* bo  = (const float*)d_in[5];
    float* out = (float*)d_out;
    float* ws  = (float*)d_ws;

    // reset row-group counters (8 ints at the 2 MB mark — proven region)
    hipMemsetAsync((char*)d_ws + (size_t)2 * BB * HH * 4, 0, 64, stream);

    void* args[] = {(void*)&x, (void*)&Whx, (void*)&Whh, (void*)&Wph,
                    (void*)&bh, (void*)&bo, (void*)&out, (void*)&ws};
    hipLaunchCooperativeKernel((void*)rnn_persist, dim3(NGRP * NCT), dim3(NTH),
                               args, 0, stream);
}